// Round 3
// baseline (9092.900 us; speedup 1.0000x reference)
//
#include <hip/hip_runtime.h>
#include <hip/hip_bf16.h>
#include <math.h>

// Problem constants
#define T_STEPS 16
#define N_NODES 20
#define BATCH 4096
#define F_DIM 64
#define BN 81920           // BATCH*N_NODES
#define E_EDGES 327680
#define D1 1280
#define D2 640
#define D3 320
#define OUT_DIM 2

static __device__ __forceinline__ float bf2f(__hip_bfloat16 v) { return __bfloat162float(v); }
static __device__ __forceinline__ float sigmoidf_(float x) { return 1.f / (1.f + expf(-x)); }
// dtype-flagged load: isf32 ? f32 : bf16
static __device__ __forceinline__ float loadf(const void* p, size_t i, int isf32) {
    return isf32 ? ((const float*)p)[i] : bf2f(((const __hip_bfloat16*)p)[i]);
}

// ---------------- dtype detection ----------------
// Interpret first 256 halfwords of x as bf16. True bf16 N(0,1) data: exponent <= ~130.
// f32 data read as bf16: even halfwords are f32 mantissa bits -> uniform random exponent,
// ~45% have exp >= 141 (|v| >= 16384 or inf/nan). 128 even samples => detection certain.
// flag = 1 => inputs are float32 ; flag = 0 => inputs are bf16.
__global__ void detect_dtype(const void* __restrict__ x, int* __restrict__ flag) {
    int lane = threadIdx.x;  // 64 threads
    const unsigned short* u = (const unsigned short*)x;
    int bad = 0;
    for (int i = lane; i < 256; i += 64) {
        int e = (u[i] >> 7) & 0xFF;
        if (e >= 141) bad = 1;
    }
    unsigned long long m = __ballot(bad != 0);
    if (lane == 0) flag[0] = (m != 0ull) ? 1 : 0;
}

// ---------------- setup kernels ----------------

__global__ void deg_count_kernel(const int* __restrict__ ei, const void* __restrict__ ew,
                                 float* __restrict__ deg, int* __restrict__ counts,
                                 const int* __restrict__ flagp) {
    int isf32 = *flagp;
    int e = blockIdx.x * 256 + threadIdx.x;
    if (e < E_EDGES) {
        atomicAdd(&deg[ei[e]], loadf(ew, e, isf32));
        atomicAdd(&counts[ei[E_EDGES + e]], 1);
    }
}

// single block, 1024 threads, 80 elements each: exclusive scan of counts -> rowptr, cursor.
__global__ void scan_kernel(const int* __restrict__ counts, int* __restrict__ rowptr,
                            int* __restrict__ cursor) {
    __shared__ int s[1024];
    int t = threadIdx.x;
    int base = t * 80;
    int sum = 0;
    for (int i = 0; i < 80; ++i) sum += counts[base + i];
    s[t] = sum;
    __syncthreads();
    for (int off = 1; off < 1024; off <<= 1) {
        int v = (t >= off) ? s[t - off] : 0;
        __syncthreads();
        s[t] += v;
        __syncthreads();
    }
    int run = (t > 0) ? s[t - 1] : 0;
    for (int i = 0; i < 80; ++i) {
        rowptr[base + i] = run;
        cursor[base + i] = run;
        run += counts[base + i];
    }
    if (t == 1023) rowptr[BN] = run;
}

__global__ void fill_kernel(const int* __restrict__ ei, const void* __restrict__ ew,
                            const float* __restrict__ deg,
                            int* __restrict__ cursor, int* __restrict__ csr_col,
                            float* __restrict__ csr_val, const int* __restrict__ flagp) {
    int isf32 = *flagp;
    int e = blockIdx.x * 256 + threadIdx.x;
    if (e < E_EDGES) {
        int s = ei[e], d = ei[E_EDGES + e];
        float w = loadf(ew, e, isf32);
        float ds = deg[s], dd = deg[d];
        float is = (ds > 0.f) ? (1.f / sqrtf(ds)) : 0.f;
        float id = (dd > 0.f) ? (1.f / sqrtf(dd)) : 0.f;
        int p = atomicAdd(&cursor[d], 1);
        csr_col[p] = s;
        csr_val[p] = -is * w * id;
    }
}

// Combined-weight prep (all outputs f32):
// Wg[384][192]: K-rows m=0..5 <- {X:(W0-W2), X:W1, X:2*W2, H:(W0-W2), H:W1, H:2*W2}
//               col groups: [0:64) z, [64:128) r, [128:192) hx (H-part zero)
// Wc[192][64] from Whh; plus f32 copies of W1,W2,W3 and all biases.
__global__ void prep_weights(const void* Wxz, const void* Whz,
                             const void* Wxr, const void* Whr,
                             const void* Wxh, const void* Whh,
                             const void* bxz, const void* bhz,
                             const void* bxr, const void* bhr,
                             const void* bxh, const void* bhh,
                             const void* W1, const void* b1,
                             const void* W2, const void* b2,
                             const void* W3, const void* b3,
                             float* Wg, float* Wc, float* biasg, float* biasc,
                             float* W1f, float* bias1, float* W2f, float* bias2,
                             float* W3f, float* b3f, const int* __restrict__ flagp) {
    int isf32 = *flagp;
    int tid = blockIdx.x * 256 + threadIdx.x;
    if (tid < 73728) {
        int j = tid / 192, c = tid - (tid / 192) * 192;
        int m = j >> 6, jj = j & 63;
        int grp = c >> 6, cc = c & 63;
        const void* Wx = (grp == 0) ? Wxz : ((grp == 1) ? Wxr : Wxh);
        const void* Wh = (grp == 0) ? Whz : ((grp == 1) ? Whr : nullptr);
        float v = 0.f;
        int o = jj * 64 + cc;
        if (m < 3) {
            if (m == 0)      v = loadf(Wx, o, isf32) - loadf(Wx, 2 * 4096 + o, isf32);
            else if (m == 1) v = loadf(Wx, 4096 + o, isf32);
            else             v = 2.f * loadf(Wx, 2 * 4096 + o, isf32);
        } else if (Wh) {
            int mm = m - 3;
            if (mm == 0)      v = loadf(Wh, o, isf32) - loadf(Wh, 2 * 4096 + o, isf32);
            else if (mm == 1) v = loadf(Wh, 4096 + o, isf32);
            else              v = 2.f * loadf(Wh, 2 * 4096 + o, isf32);
        }
        Wg[j * 192 + c] = v;
    } else if (tid < 86016) {
        int t2 = tid - 73728;
        int j = t2 >> 6, c = t2 & 63;
        int m = j >> 6, jj = j & 63;
        int o = jj * 64 + c;
        float v;
        if (m == 0)      v = loadf(Whh, o, isf32) - loadf(Whh, 2 * 4096 + o, isf32);
        else if (m == 1) v = loadf(Whh, 4096 + o, isf32);
        else             v = 2.f * loadf(Whh, 2 * 4096 + o, isf32);
        Wc[j * 64 + c] = v;
    } else if (tid < 86208) {
        int c = tid - 86016;
        int grp = c >> 6, cc = c & 63;
        float v = (grp == 0) ? (loadf(bxz, cc, isf32) + loadf(bhz, cc, isf32))
                 : (grp == 1) ? (loadf(bxr, cc, isf32) + loadf(bhr, cc, isf32))
                              : loadf(bxh, cc, isf32);
        biasg[c] = v;
    } else if (tid < 86272) {
        biasc[tid - 86208] = loadf(bhh, tid - 86208, isf32);
    } else if (tid < 86912) {
        bias1[tid - 86272] = loadf(b1, tid - 86272, isf32);
    } else if (tid < 87232) {
        bias2[tid - 86912] = loadf(b2, tid - 86912, isf32);
    } else if (tid < 87872) {
        W3f[tid - 87232] = loadf(W3, tid - 87232, isf32);
    } else if (tid < 87874) {
        b3f[tid - 87872] = loadf(b3, tid - 87872, isf32);
    } else if (tid < 907074) {
        W1f[tid - 87874] = loadf(W1, tid - 87874, isf32);
    } else if (tid < 1111874) {
        W2f[tid - 907074] = loadf(W2, tid - 907074, isf32);
    }
}

// ---------------- per-step kernels ----------------

// copy x_t (element offset eoff) into A6 cols 0:64, converting to f32
__global__ void copy_x_off(const void* __restrict__ x, float* __restrict__ A6,
                           const int* __restrict__ flagp, unsigned long long eoff) {
    int isf32 = *flagp;
    int idx = blockIdx.x * 256 + threadIdx.x;   // 81920*64
    int r = idx >> 6, f = idx & 63;
    A6[(size_t)r * 384 + f] = loadf(x, (size_t)eoff + idx, isf32);
}

__global__ void copy_h(const float* __restrict__ A6, float* __restrict__ Hd) {
    int idx = blockIdx.x * 256 + threadIdx.x;
    int r = idx >> 6, f = idx & 63;
    Hd[idx] = A6[(size_t)r * 384 + 192 + f];
}

// one wave per row; lane = feature; pure f32
__global__ void spmm_kernel(const int* __restrict__ rowptr, const int* __restrict__ col,
                            const float* __restrict__ val, const float* __restrict__ in,
                            int in_stride, float* __restrict__ out, int out_stride) {
    int row = blockIdx.x * 4 + (threadIdx.x >> 6);
    int lane = threadIdx.x & 63;
    int e0 = rowptr[row], e1 = rowptr[row + 1];
    float acc = 0.f;
    for (int e = e0; e < e1; ++e) {
        int s = col[e];
        float v = val[e];
        acc = fmaf(v, in[(size_t)s * in_stride + lane], acc);
    }
    out[(size_t)row * out_stride + lane] = acc;
}

// Tiled fp32 GEMM: C[M x Ntot] = epi(A[M x K] @ W[K x Ntot] + bias)
// EPI: 0 = relu -> C;  1 = gates (Z=sig, G=sig(R)*H into A6 cols 0:64, hx);  2 = cand + GRU
template <int TG, int EPI>
__launch_bounds__(256)
__global__ void gemm_kernel(const float* __restrict__ A, int lda,
                            const float* __restrict__ W, int ldw,
                            const float* __restrict__ bias,
                            float* __restrict__ C, int ldc, int K,
                            float* __restrict__ Zbuf, float* __restrict__ hxbuf,
                            float* A6) {
    constexpr int TN = 64 * TG;
    __shared__ __align__(16) float As[16][68];
    __shared__ __align__(16) float Ws[16][TN + 4];
    int tid = threadIdx.x;
    int tx = tid & 15, ty = tid >> 4;
    int row0 = blockIdx.x * 64;
    int n_base = blockIdx.y * TN;

    float acc[TG][4][4];
    for (int g = 0; g < TG; ++g)
        for (int i = 0; i < 4; ++i)
            for (int j = 0; j < 4; ++j) acc[g][i][j] = 0.f;

    for (int k0 = 0; k0 < K; k0 += 16) {
        for (int i = tid; i < 64 * 16; i += 256) {
            int r = i >> 4, k = i & 15;
            As[k][r] = A[(size_t)(row0 + r) * lda + k0 + k];
        }
        for (int i = tid; i < 16 * TN; i += 256) {
            int k = i / TN, n = i - k * TN;
            Ws[k][n] = W[(size_t)(k0 + k) * ldw + n_base + n];
        }
        __syncthreads();
        for (int k = 0; k < 16; ++k) {
            float4 a4 = *(const float4*)&As[k][ty * 4];
            float av[4] = {a4.x, a4.y, a4.z, a4.w};
            for (int g = 0; g < TG; ++g) {
                float4 b4 = *(const float4*)&Ws[k][g * 64 + tx * 4];
                float bv[4] = {b4.x, b4.y, b4.z, b4.w};
                for (int i = 0; i < 4; ++i)
                    for (int j = 0; j < 4; ++j)
                        acc[g][i][j] = fmaf(av[i], bv[j], acc[g][i][j]);
            }
        }
        __syncthreads();
    }

    for (int g = 0; g < TG; ++g) {
        for (int i = 0; i < 4; ++i) {
            int r = row0 + ty * 4 + i;
            for (int j = 0; j < 4; ++j) {
                int cl = g * 64 + tx * 4 + j;
                float v = acc[g][i][j];
                if (EPI == 0) {
                    int c = n_base + cl;
                    C[(size_t)r * ldc + c] = fmaxf(v + bias[c], 0.f);
                } else if (EPI == 1) {
                    if (g == 0) {
                        Zbuf[(size_t)r * 64 + cl] = sigmoidf_(v + bias[cl]);
                    } else if (g == 1) {
                        int cc = cl - 64;
                        float rv = sigmoidf_(v + bias[cl]);
                        A6[(size_t)r * 384 + cc] = rv * A6[(size_t)r * 384 + 192 + cc];
                    } else {
                        int cc = cl - 128;
                        hxbuf[(size_t)r * 64 + cc] = v + bias[cl];
                    }
                } else {  // EPI == 2
                    int cc = cl;
                    float pre = v + bias[cc] + hxbuf[(size_t)r * 64 + cc];
                    float ht = tanhf(pre);
                    float z = Zbuf[(size_t)r * 64 + cc];
                    float* hp = &A6[(size_t)r * 384 + 192 + cc];
                    float h = *hp;
                    float hn = z * h + (1.f - z) * ht;
                    *hp = fmaxf(hn, 0.f);
                }
            }
        }
    }
}

// final layer + softmax over 2 classes; one wave per batch row; dual-dtype store
__global__ void mlp3_kernel(const float* __restrict__ h2, const float* __restrict__ W3f,
                            const float* __restrict__ b3f, void* __restrict__ out,
                            const int* __restrict__ flagp) {
    int isf32 = *flagp;
    int b = blockIdx.x * 4 + (threadIdx.x >> 6);
    int lane = threadIdx.x & 63;
    float a0 = 0.f, a1 = 0.f;
    for (int k = lane; k < D3; k += 64) {
        float h = h2[(size_t)b * D3 + k];
        a0 = fmaf(h, W3f[k * 2 + 0], a0);
        a1 = fmaf(h, W3f[k * 2 + 1], a1);
    }
    for (int off = 32; off; off >>= 1) {
        a0 += __shfl_down(a0, off, 64);
        a1 += __shfl_down(a1, off, 64);
    }
    if (lane == 0) {
        a0 += b3f[0];
        a1 += b3f[1];
        float m = fmaxf(a0, a1);
        float e0 = expf(a0 - m), e1 = expf(a1 - m);
        float s = e0 + e1;
        if (isf32) {
            ((float*)out)[b * 2 + 0] = e0 / s;
            ((float*)out)[b * 2 + 1] = e1 / s;
        } else {
            ((__hip_bfloat16*)out)[b * 2 + 0] = __float2bfloat16(e0 / s);
            ((__hip_bfloat16*)out)[b * 2 + 1] = __float2bfloat16(e1 / s);
        }
    }
}

// ---------------- host ----------------

extern "C" void kernel_launch(void* const* d_in, const int* in_sizes, int n_in,
                              void* d_out, int out_size, void* d_ws, size_t ws_size,
                              hipStream_t stream) {
    const void* x   = d_in[0];
    const int*  ei  = (const int*)d_in[1];
    const void* ew  = d_in[2];
    const void* Wxz = d_in[3];
    const void* bxz = d_in[4];
    const void* Whz = d_in[5];
    const void* bhz = d_in[6];
    const void* Wxr = d_in[7];
    const void* bxr = d_in[8];
    const void* Whr = d_in[9];
    const void* bhr = d_in[10];
    const void* Wxh = d_in[11];
    const void* bxh = d_in[12];
    const void* Whh = d_in[13];
    const void* bhh = d_in[14];
    const void* W1  = d_in[15];
    const void* b1  = d_in[16];
    const void* W2  = d_in[17];
    const void* b2  = d_in[18];
    const void* W3  = d_in[19];
    const void* b3  = d_in[20];

    // workspace layout
    char* ws = (char*)d_ws;
    size_t off = 0;
    auto alloc = [&](size_t bytes) { char* p = ws + off; off += (bytes + 255) & ~(size_t)255; return p; };
    float* A6     = (float*)alloc((size_t)BN * 384 * 4);   // [X|X1|X2|H|H1|H2] (X->G chain reuse)
    float* Zbuf   = (float*)alloc((size_t)BN * 64 * 4);    // Z; later Hdense
    float* hxbuf  = (float*)alloc((size_t)BN * 64 * 4);    // hx; later h1
    float* h2buf  = (float*)alloc((size_t)BATCH * D3 * 4);
    float* deg    = (float*)alloc((size_t)BN * 4);
    int*   counts = (int*)alloc((size_t)BN * 4);
    int*   rowptr = (int*)alloc((size_t)(BN + 1) * 4);
    int*   cursor = (int*)alloc((size_t)BN * 4);
    int*   ccol   = (int*)alloc((size_t)E_EDGES * 4);
    float* cval   = (float*)alloc((size_t)E_EDGES * 4);
    float* Wg     = (float*)alloc(384 * 192 * 4);
    float* Wc     = (float*)alloc(192 * 64 * 4);
    float* biasg  = (float*)alloc(192 * 4);
    float* biasc  = (float*)alloc(64 * 4);
    float* W1f    = (float*)alloc((size_t)D1 * D2 * 4);
    float* bias1  = (float*)alloc(D2 * 4);
    float* W2f    = (float*)alloc((size_t)D2 * D3 * 4);
    float* bias2  = (float*)alloc(D3 * 4);
    float* W3f    = (float*)alloc(D3 * 2 * 4);
    float* b3f    = (float*)alloc(2 * 4);
    int*   flag   = (int*)alloc(256);
    (void)ws_size; (void)in_sizes; (void)n_in; (void)out_size;

    hipMemsetAsync(A6, 0, (size_t)BN * 384 * 4, stream);   // H0 = 0
    hipMemsetAsync(deg, 0, (size_t)BN * 4, stream);
    hipMemsetAsync(counts, 0, (size_t)BN * 4, stream);

    detect_dtype<<<1, 64, 0, stream>>>(x, flag);

    const int EB = E_EDGES / 256;  // 1280
    deg_count_kernel<<<EB, 256, 0, stream>>>(ei, ew, deg, counts, flag);
    scan_kernel<<<1, 1024, 0, stream>>>(counts, rowptr, cursor);
    fill_kernel<<<EB, 256, 0, stream>>>(ei, ew, deg, cursor, ccol, cval, flag);
    prep_weights<<<4344, 256, 0, stream>>>(Wxz, Whz, Wxr, Whr, Wxh, Whh,
                                           bxz, bhz, bxr, bhr, bxh, bhh,
                                           W1, b1, W2, b2, W3, b3,
                                           Wg, Wc, biasg, biasc,
                                           W1f, bias1, W2f, bias2, W3f, b3f, flag);

    const int RB = BN / 4;            // 20480 blocks for wave-per-row kernels
    const int CB = (BN * 64) / 256;   // 20480 for copy kernels
    for (int t = 0; t < T_STEPS; ++t) {
        unsigned long long eoff = (unsigned long long)t * BN * 64;
        copy_x_off<<<CB, 256, 0, stream>>>(x, A6, flag, eoff);
        spmm_kernel<<<RB, 256, 0, stream>>>(rowptr, ccol, cval, A6,       384, A6 + 64,  384);  // X1
        spmm_kernel<<<RB, 256, 0, stream>>>(rowptr, ccol, cval, A6 + 64,  384, A6 + 128, 384);  // X2
        spmm_kernel<<<RB, 256, 0, stream>>>(rowptr, ccol, cval, A6 + 192, 384, A6 + 256, 384);  // H1
        spmm_kernel<<<RB, 256, 0, stream>>>(rowptr, ccol, cval, A6 + 256, 384, A6 + 320, 384);  // H2
        gemm_kernel<3, 1><<<dim3(BN / 64, 1), 256, 0, stream>>>(
            A6, 384, Wg, 192, biasg, nullptr, 0, 384, Zbuf, hxbuf, A6);
        spmm_kernel<<<RB, 256, 0, stream>>>(rowptr, ccol, cval, A6,       384, A6 + 64,  384);  // G1
        spmm_kernel<<<RB, 256, 0, stream>>>(rowptr, ccol, cval, A6 + 64,  384, A6 + 128, 384);  // G2
        gemm_kernel<1, 2><<<dim3(BN / 64, 1), 256, 0, stream>>>(
            A6, 384, Wc, 64, biasc, nullptr, 0, 192, Zbuf, hxbuf, A6);
    }

    copy_h<<<CB, 256, 0, stream>>>(A6, Zbuf);  // Hdense [4096 x 1280] in Zbuf
    gemm_kernel<1, 0><<<dim3(BATCH / 64, D2 / 64), 256, 0, stream>>>(
        Zbuf, D1, W1f, D2, bias1, hxbuf, D2, D1, nullptr, nullptr, nullptr);   // h1
    gemm_kernel<1, 0><<<dim3(BATCH / 64, D3 / 64), 256, 0, stream>>>(
        hxbuf, D2, W2f, D3, bias2, h2buf, D3, D2, nullptr, nullptr, nullptr);  // h2
    mlp3_kernel<<<BATCH / 4, 256, 0, stream>>>(h2buf, W3f, b3f, d_out, flag);
}

// Round 4
// 5800.146 us; speedup vs baseline: 1.5677x; 1.5677x over previous
//
#include <hip/hip_runtime.h>
#include <hip/hip_bf16.h>
#include <math.h>

#define T_STEPS 16
#define N_NODES 20
#define BATCH 4096
#define F_DIM 64
#define BN 81920
#define E_EDGES 327680
#define D1 1280
#define D2 640
#define D3 320

typedef __attribute__((ext_vector_type(8))) short short8;
typedef __attribute__((ext_vector_type(4))) float floatx4;

static __device__ __forceinline__ float bf2f(__hip_bfloat16 v) { return __bfloat162float(v); }
static __device__ __forceinline__ float sigmoidf_(float x) { return 1.f / (1.f + expf(-x)); }
static __device__ __forceinline__ float loadf(const void* p, size_t i, int isf32) {
    return isf32 ? ((const float*)p)[i] : bf2f(((const __hip_bfloat16*)p)[i]);
}

// ---------------- dtype detection (bf16 vs f32 inputs) ----------------
__global__ void detect_dtype(const void* __restrict__ x, int* __restrict__ flag) {
    int lane = threadIdx.x;
    const unsigned short* u = (const unsigned short*)x;
    int bad = 0;
    for (int i = lane; i < 256; i += 64) {
        int e = (u[i] >> 7) & 0xFF;
        if (e >= 141) bad = 1;
    }
    unsigned long long m = __ballot(bad != 0);
    if (lane == 0) flag[0] = (m != 0ull) ? 1 : 0;
}

// ---------------- CSR build ----------------
__global__ void deg_count_kernel(const int* __restrict__ ei, const void* __restrict__ ew,
                                 float* __restrict__ deg, int* __restrict__ counts,
                                 const int* __restrict__ flagp) {
    int isf32 = *flagp;
    int e = blockIdx.x * 256 + threadIdx.x;
    if (e < E_EDGES) {
        atomicAdd(&deg[ei[e]], loadf(ew, e, isf32));
        atomicAdd(&counts[ei[E_EDGES + e]], 1);
    }
}

__global__ void scan_kernel(const int* __restrict__ counts, int* __restrict__ rowptr,
                            int* __restrict__ cursor) {
    __shared__ int s[1024];
    int t = threadIdx.x;
    int base = t * 80;
    int sum = 0;
    for (int i = 0; i < 80; ++i) sum += counts[base + i];
    s[t] = sum;
    __syncthreads();
    for (int off = 1; off < 1024; off <<= 1) {
        int v = (t >= off) ? s[t - off] : 0;
        __syncthreads();
        s[t] += v;
        __syncthreads();
    }
    int run = (t > 0) ? s[t - 1] : 0;
    for (int i = 0; i < 80; ++i) {
        rowptr[base + i] = run;
        cursor[base + i] = run;
        run += counts[base + i];
    }
    if (t == 1023) rowptr[BN] = run;
}

__global__ void fill_kernel(const int* __restrict__ ei, const void* __restrict__ ew,
                            const float* __restrict__ deg,
                            int* __restrict__ cursor, int* __restrict__ csr_col,
                            float* __restrict__ csr_val, const int* __restrict__ flagp) {
    int isf32 = *flagp;
    int e = blockIdx.x * 256 + threadIdx.x;
    if (e < E_EDGES) {
        int s = ei[e], d = ei[E_EDGES + e];
        float w = loadf(ew, e, isf32);
        float ds = deg[s], dd = deg[d];
        float is = (ds > 0.f) ? (1.f / sqrtf(ds)) : 0.f;
        float id = (dd > 0.f) ? (1.f / sqrtf(dd)) : 0.f;
        int p = atomicAdd(&cursor[d], 1);
        csr_col[p] = s;
        csr_val[p] = -is * w * id;
    }
}

// ---------------- weight prep: transposed bf16 (N x K row-major) ----------------
// WgT[192][384]: n = grp*64+cc (z|r|hx), k = m*64+jj, m in {X0,X1,X2,H0,H1,H2}
// WcT[64][192] from Whh; W1T[640][1280]; W2T[320][640]; f32 biases + W3.
__global__ void prep_weights(const void* Wxz, const void* Whz,
                             const void* Wxr, const void* Whr,
                             const void* Wxh, const void* Whh,
                             const void* bxz, const void* bhz,
                             const void* bxr, const void* bhr,
                             const void* bxh, const void* bhh,
                             const void* W1, const void* b1,
                             const void* W2, const void* b2,
                             const void* W3, const void* b3,
                             __hip_bfloat16* WgT, __hip_bfloat16* WcT,
                             float* biasg, float* biasc,
                             __hip_bfloat16* W1T, float* bias1,
                             __hip_bfloat16* W2T, float* bias2,
                             float* W3f, float* b3f, const int* __restrict__ flagp) {
    int isf32 = *flagp;
    int tid = blockIdx.x * 256 + threadIdx.x;
    if (tid < 73728) {
        int n = tid / 384, kk = tid - (tid / 384) * 384;
        int m = kk >> 6, jj = kk & 63;
        int grp = n >> 6, cc = n & 63;
        const void* Wx = (grp == 0) ? Wxz : ((grp == 1) ? Wxr : Wxh);
        const void* Wh = (grp == 0) ? Whz : ((grp == 1) ? Whr : nullptr);
        float v = 0.f;
        int o = jj * 64 + cc;
        if (m < 3) {
            if (m == 0)      v = loadf(Wx, o, isf32) - loadf(Wx, 2 * 4096 + o, isf32);
            else if (m == 1) v = loadf(Wx, 4096 + o, isf32);
            else             v = 2.f * loadf(Wx, 2 * 4096 + o, isf32);
        } else if (Wh) {
            int mm = m - 3;
            if (mm == 0)      v = loadf(Wh, o, isf32) - loadf(Wh, 2 * 4096 + o, isf32);
            else if (mm == 1) v = loadf(Wh, 4096 + o, isf32);
            else              v = 2.f * loadf(Wh, 2 * 4096 + o, isf32);
        }
        WgT[tid] = __float2bfloat16(v);
    } else if (tid < 86016) {
        int t2 = tid - 73728;
        int n = t2 / 192, kk = t2 - (t2 / 192) * 192;
        int m = kk >> 6, jj = kk & 63;
        int o = jj * 64 + n;
        float v;
        if (m == 0)      v = loadf(Whh, o, isf32) - loadf(Whh, 2 * 4096 + o, isf32);
        else if (m == 1) v = loadf(Whh, 4096 + o, isf32);
        else             v = 2.f * loadf(Whh, 2 * 4096 + o, isf32);
        WcT[t2] = __float2bfloat16(v);
    } else if (tid < 86208) {
        int c = tid - 86016;
        int grp = c >> 6, cc = c & 63;
        float v = (grp == 0) ? (loadf(bxz, cc, isf32) + loadf(bhz, cc, isf32))
                 : (grp == 1) ? (loadf(bxr, cc, isf32) + loadf(bhr, cc, isf32))
                              : loadf(bxh, cc, isf32);
        biasg[c] = v;
    } else if (tid < 86272) {
        biasc[tid - 86208] = loadf(bhh, tid - 86208, isf32);
    } else if (tid < 86912) {
        bias1[tid - 86272] = loadf(b1, tid - 86272, isf32);
    } else if (tid < 87232) {
        bias2[tid - 86912] = loadf(b2, tid - 86912, isf32);
    } else if (tid < 87872) {
        W3f[tid - 87232] = loadf(W3, tid - 87232, isf32);
    } else if (tid < 87874) {
        b3f[tid - 87872] = loadf(b3, tid - 87872, isf32);
    } else if (tid < 907074) {
        int t = tid - 87874;                       // W1T[n][k] = W1[k][n]
        int n = t / 1280, k = t - (t / 1280) * 1280;
        W1T[t] = __float2bfloat16(loadf(W1, (size_t)k * 640 + n, isf32));
    } else if (tid < 1111874) {
        int t = tid - 907074;                      // W2T[n][k] = W2[k][n]
        int n = t / 640, k = t - (t / 640) * 640;
        W2T[t] = __float2bfloat16(loadf(W2, (size_t)k * 320 + n, isf32));
    }
}

// ---------------- per-step: fused gathers on bf16 A6 ----------------
// A6 row stride 384: cols [X:0 | X1:64 | X2:128 | H:192 | H1:256 | H2:320]

// phaseA: X = x_t (converted), X1 = L x_t, H1 = L H. One wave per row.
__global__ void phaseA_kernel(const int* __restrict__ rowptr, const int* __restrict__ col,
                              const float* __restrict__ val, const void* __restrict__ x,
                              const int* __restrict__ flagp, unsigned long long eoff,
                              __hip_bfloat16* __restrict__ A6) {
    int isf32 = *flagp;
    int row = blockIdx.x * 4 + (threadIdx.x >> 6);
    int lane = threadIdx.x & 63;
    int e0 = rowptr[row], e1 = rowptr[row + 1];
    float xv = loadf(x, (size_t)eoff + (size_t)row * 64 + lane, isf32);
    float ax = 0.f, ah = 0.f;
    for (int e = e0; e < e1; ++e) {
        int s = col[e];
        float v = val[e];
        ax = fmaf(v, loadf(x, (size_t)eoff + (size_t)s * 64 + lane, isf32), ax);
        ah = fmaf(v, bf2f(A6[(size_t)s * 384 + 192 + lane]), ah);
    }
    size_t rb = (size_t)row * 384;
    A6[rb + lane]       = __float2bfloat16(xv);
    A6[rb + 64 + lane]  = __float2bfloat16(ax);
    A6[rb + 256 + lane] = __float2bfloat16(ah);
}

// phaseB: X2 = L X1, H2 = L H1
__global__ void phaseB_kernel(const int* __restrict__ rowptr, const int* __restrict__ col,
                              const float* __restrict__ val,
                              __hip_bfloat16* __restrict__ A6) {
    int row = blockIdx.x * 4 + (threadIdx.x >> 6);
    int lane = threadIdx.x & 63;
    int e0 = rowptr[row], e1 = rowptr[row + 1];
    float ax = 0.f, ah = 0.f;
    for (int e = e0; e < e1; ++e) {
        int s = col[e];
        float v = val[e];
        size_t sb = (size_t)s * 384;
        ax = fmaf(v, bf2f(A6[sb + 64 + lane]), ax);
        ah = fmaf(v, bf2f(A6[sb + 256 + lane]), ah);
    }
    size_t rb = (size_t)row * 384;
    A6[rb + 128 + lane] = __float2bfloat16(ax);
    A6[rb + 320 + lane] = __float2bfloat16(ah);
}

// generic single spmm on A6 bf16 cols (G-chain)
__global__ void spmm_b_kernel(const int* __restrict__ rowptr, const int* __restrict__ col,
                              const float* __restrict__ val,
                              __hip_bfloat16* __restrict__ A6, int in_off, int out_off) {
    int row = blockIdx.x * 4 + (threadIdx.x >> 6);
    int lane = threadIdx.x & 63;
    int e0 = rowptr[row], e1 = rowptr[row + 1];
    float acc = 0.f;
    for (int e = e0; e < e1; ++e) {
        int s = col[e];
        acc = fmaf(val[e], bf2f(A6[(size_t)s * 384 + in_off + lane]), acc);
    }
    A6[(size_t)row * 384 + out_off + lane] = __float2bfloat16(acc);
}

// ---------------- MFMA GEMM (fragment-direct, no LDS) ----------------
// C[M x N] = epi(A[M x K]_bf16 @ WT[N x K]_bf16^T + bias)
// 256 thr = 4 waves; wave covers MW*16 rows; block covers MW*64 rows, NT*16 cols.
// Layouts (gfx950 mfma_f32_16x16x32_bf16, guide-verified):
//   A-frag: lane holds A[m=lane&15][k = quad*8 + 0..7] (16B contiguous)
//   B-frag: lane holds B[k = quad*8 + 0..7][n=lane&15]  -> WT[n][k] 16B contiguous
//   C/D:    lane,reg -> D[row = quad*4+reg][col = lane&15]
// EPI: 0 = relu -> C(bf16); 1 = gates (Z f32, G=sig(R)*Hf -> A6 col0, hx f32); 2 = cand+GRU
template <int MW, int NT, int EPI>
__launch_bounds__(256)
__global__ void mfma_gemm(const __hip_bfloat16* __restrict__ A, int lda,
                          const __hip_bfloat16* __restrict__ WT, int ldk,
                          const float* __restrict__ bias, int K,
                          float* __restrict__ Zbuf, float* __restrict__ hxbuf,
                          float* __restrict__ Hf, __hip_bfloat16* A6,
                          __hip_bfloat16* __restrict__ C, int ldc) {
    int wave = threadIdx.x >> 6;
    int lane = threadIdx.x & 63;
    int l15 = lane & 15, quad = lane >> 4;
    int m0 = blockIdx.x * (MW * 64) + wave * (MW * 16);
    int n0 = blockIdx.y * (NT * 16);

    floatx4 acc[MW][NT];
#pragma unroll
    for (int mi = 0; mi < MW; ++mi)
#pragma unroll
        for (int nt = 0; nt < NT; ++nt) acc[mi][nt] = (floatx4){0.f, 0.f, 0.f, 0.f};

    for (int k0 = 0; k0 < K; k0 += 32) {
        short8 a[MW];
#pragma unroll
        for (int mi = 0; mi < MW; ++mi)
            a[mi] = *(const short8*)(A + (size_t)(m0 + mi * 16 + l15) * lda + k0 + quad * 8);
#pragma unroll
        for (int nt = 0; nt < NT; ++nt) {
            short8 b = *(const short8*)(WT + (size_t)(n0 + nt * 16 + l15) * ldk + k0 + quad * 8);
#pragma unroll
            for (int mi = 0; mi < MW; ++mi)
                acc[mi][nt] = __builtin_amdgcn_mfma_f32_16x16x32_bf16(a[mi], b, acc[mi][nt], 0, 0, 0);
        }
    }

#pragma unroll
    for (int mi = 0; mi < MW; ++mi)
#pragma unroll
        for (int nt = 0; nt < NT; ++nt) {
            int cl = n0 + nt * 16 + l15;
#pragma unroll
            for (int reg = 0; reg < 4; ++reg) {
                int r = m0 + mi * 16 + quad * 4 + reg;
                float v = acc[mi][nt][reg];
                if (EPI == 0) {
                    C[(size_t)r * ldc + cl] = __float2bfloat16(fmaxf(v + bias[cl], 0.f));
                } else if (EPI == 1) {
                    v += bias[cl];
                    if (cl < 64) {
                        Zbuf[(size_t)r * 64 + cl] = sigmoidf_(v);
                    } else if (cl < 128) {
                        int cc = cl - 64;
                        float g = sigmoidf_(v) * Hf[(size_t)r * 64 + cc];
                        A6[(size_t)r * 384 + cc] = __float2bfloat16(g);
                    } else {
                        int cc = cl - 128;
                        hxbuf[(size_t)r * 64 + cc] = v;
                    }
                } else {
                    float pre = v + bias[cl] + hxbuf[(size_t)r * 64 + cl];
                    float ht = tanhf(pre);
                    float z = Zbuf[(size_t)r * 64 + cl];
                    float h = Hf[(size_t)r * 64 + cl];
                    float hn = fmaxf(z * h + (1.f - z) * ht, 0.f);
                    Hf[(size_t)r * 64 + cl] = hn;
                    A6[(size_t)r * 384 + 192 + cl] = __float2bfloat16(hn);
                }
            }
        }
}

// Hf f32 [BN x 64] flat == Hdense [4096 x 1280] flat; convert to bf16
__global__ void convert_h(const float* __restrict__ Hf, __hip_bfloat16* __restrict__ Hd) {
    int idx = blockIdx.x * 256 + threadIdx.x;
    Hd[idx] = __float2bfloat16(Hf[idx]);
}

// final layer + softmax(2); one wave per batch row
__global__ void mlp3_kernel(const __hip_bfloat16* __restrict__ h2, const float* __restrict__ W3f,
                            const float* __restrict__ b3f, void* __restrict__ out,
                            const int* __restrict__ flagp) {
    int isf32 = *flagp;
    int b = blockIdx.x * 4 + (threadIdx.x >> 6);
    int lane = threadIdx.x & 63;
    float a0 = 0.f, a1 = 0.f;
    for (int k = lane; k < D3; k += 64) {
        float h = bf2f(h2[(size_t)b * D3 + k]);
        a0 = fmaf(h, W3f[k * 2 + 0], a0);
        a1 = fmaf(h, W3f[k * 2 + 1], a1);
    }
    for (int off = 32; off; off >>= 1) {
        a0 += __shfl_down(a0, off, 64);
        a1 += __shfl_down(a1, off, 64);
    }
    if (lane == 0) {
        a0 += b3f[0];
        a1 += b3f[1];
        float m = fmaxf(a0, a1);
        float e0 = expf(a0 - m), e1 = expf(a1 - m);
        float s = e0 + e1;
        if (isf32) {
            ((float*)out)[b * 2 + 0] = e0 / s;
            ((float*)out)[b * 2 + 1] = e1 / s;
        } else {
            ((__hip_bfloat16*)out)[b * 2 + 0] = __float2bfloat16(e0 / s);
            ((__hip_bfloat16*)out)[b * 2 + 1] = __float2bfloat16(e1 / s);
        }
    }
}

// ---------------- host ----------------
extern "C" void kernel_launch(void* const* d_in, const int* in_sizes, int n_in,
                              void* d_out, int out_size, void* d_ws, size_t ws_size,
                              hipStream_t stream) {
    const void* x   = d_in[0];
    const int*  ei  = (const int*)d_in[1];
    const void* ew  = d_in[2];
    const void* Wxz = d_in[3];
    const void* bxz = d_in[4];
    const void* Whz = d_in[5];
    const void* bhz = d_in[6];
    const void* Wxr = d_in[7];
    const void* bxr = d_in[8];
    const void* Whr = d_in[9];
    const void* bhr = d_in[10];
    const void* Wxh = d_in[11];
    const void* bxh = d_in[12];
    const void* Whh = d_in[13];
    const void* bhh = d_in[14];
    const void* W1  = d_in[15];
    const void* b1  = d_in[16];
    const void* W2  = d_in[17];
    const void* b2  = d_in[18];
    const void* W3  = d_in[19];
    const void* b3  = d_in[20];

    char* ws = (char*)d_ws;
    size_t off = 0;
    auto alloc = [&](size_t bytes) { char* p = ws + off; off += (bytes + 255) & ~(size_t)255; return p; };
    __hip_bfloat16* A6  = (__hip_bfloat16*)alloc((size_t)BN * 384 * 2);  // bf16 state
    float* Hf    = (float*)alloc((size_t)BN * 64 * 4);                   // precise H
    float* Zbuf  = (float*)alloc((size_t)BN * 64 * 4);
    float* hxbuf = (float*)alloc((size_t)BN * 64 * 4);
    __hip_bfloat16* Hd  = (__hip_bfloat16*)alloc((size_t)BN * 64 * 2);   // Hdense bf16
    __hip_bfloat16* h1  = (__hip_bfloat16*)alloc((size_t)BATCH * D2 * 2);
    __hip_bfloat16* h2  = (__hip_bfloat16*)alloc((size_t)BATCH * D3 * 2);
    float* deg    = (float*)alloc((size_t)BN * 4);
    int*   counts = (int*)alloc((size_t)BN * 4);
    int*   rowptr = (int*)alloc((size_t)(BN + 1) * 4);
    int*   cursor = (int*)alloc((size_t)BN * 4);
    int*   ccol   = (int*)alloc((size_t)E_EDGES * 4);
    float* cval   = (float*)alloc((size_t)E_EDGES * 4);
    __hip_bfloat16* WgT = (__hip_bfloat16*)alloc(192 * 384 * 2);
    __hip_bfloat16* WcT = (__hip_bfloat16*)alloc(64 * 192 * 2);
    float* biasg  = (float*)alloc(192 * 4);
    float* biasc  = (float*)alloc(64 * 4);
    __hip_bfloat16* W1T = (__hip_bfloat16*)alloc((size_t)D2 * D1 * 2);
    float* bias1  = (float*)alloc(D2 * 4);
    __hip_bfloat16* W2T = (__hip_bfloat16*)alloc((size_t)D3 * D2 * 2);
    float* bias2  = (float*)alloc(D3 * 4);
    float* W3f    = (float*)alloc(D3 * 2 * 4);
    float* b3f    = (float*)alloc(2 * 4);
    int*   flag   = (int*)alloc(256);
    (void)ws_size; (void)in_sizes; (void)n_in; (void)out_size;

    hipMemsetAsync(A6, 0, (size_t)BN * 384 * 2, stream);   // X..H2 = 0 (bf16 zero = 0x0000)
    hipMemsetAsync(Hf, 0, (size_t)BN * 64 * 4, stream);    // H0 = 0
    hipMemsetAsync(deg, 0, (size_t)BN * 4, stream);
    hipMemsetAsync(counts, 0, (size_t)BN * 4, stream);

    detect_dtype<<<1, 64, 0, stream>>>(x, flag);

    const int EB = E_EDGES / 256;
    deg_count_kernel<<<EB, 256, 0, stream>>>(ei, ew, deg, counts, flag);
    scan_kernel<<<1, 1024, 0, stream>>>(counts, rowptr, cursor);
    fill_kernel<<<EB, 256, 0, stream>>>(ei, ew, deg, cursor, ccol, cval, flag);
    prep_weights<<<4344, 256, 0, stream>>>(Wxz, Whz, Wxr, Whr, Wxh, Whh,
                                           bxz, bhz, bxr, bhr, bxh, bhh,
                                           W1, b1, W2, b2, W3, b3,
                                           WgT, WcT, biasg, biasc,
                                           W1T, bias1, W2T, bias2, W3f, b3f, flag);

    const int RB = BN / 4;  // 20480 blocks, wave-per-row
    for (int t = 0; t < T_STEPS; ++t) {
        unsigned long long eoff = (unsigned long long)t * BN * 64;
        phaseA_kernel<<<RB, 256, 0, stream>>>(rowptr, ccol, cval, x, flag, eoff, A6);
        phaseB_kernel<<<RB, 256, 0, stream>>>(rowptr, ccol, cval, A6);
        // gates: [BN x 384] @ WgT^T -> 192 cols (Z | R->G | hx)
        mfma_gemm<2, 12, 1><<<dim3(BN / 128, 1), 256, 0, stream>>>(
            A6, 384, WgT, 384, biasg, 384, Zbuf, hxbuf, Hf, A6, nullptr, 0);
        spmm_b_kernel<<<RB, 256, 0, stream>>>(rowptr, ccol, cval, A6, 0, 64);    // G1 = L G
        spmm_b_kernel<<<RB, 256, 0, stream>>>(rowptr, ccol, cval, A6, 64, 128);  // G2 = L G1
        // candidate: [BN x 192] @ WcT^T -> 64 cols, fused GRU update
        mfma_gemm<2, 4, 2><<<dim3(BN / 128, 1), 256, 0, stream>>>(
            A6, 384, WcT, 192, biasc, 192, Zbuf, hxbuf, Hf, A6, nullptr, 0);
    }

    convert_h<<<(BN * 64) / 256, 256, 0, stream>>>(Hf, Hd);
    // h1 = relu(Hd @ W1 + b1): M=4096, N=640, K=1280
    mfma_gemm<1, 4, 0><<<dim3(BATCH / 64, D2 / 64), 256, 0, stream>>>(
        Hd, D1, W1T, D1, bias1, D1, nullptr, nullptr, nullptr, nullptr, h1, D2);
    // h2 = relu(h1 @ W2 + b2): M=4096, N=320, K=640
    mfma_gemm<1, 4, 0><<<dim3(BATCH / 64, D3 / 64), 256, 0, stream>>>(
        h1, D2, W2T, D2, bias2, D2, nullptr, nullptr, nullptr, nullptr, h2, D3);
    mlp3_kernel<<<BATCH / 4, 256, 0, stream>>>(h2, W3f, b3f, d_out, flag);
}